// Round 2
// baseline (877.562 us; speedup 1.0000x reference)
//
#include <hip/hip_runtime.h>
#include <hip/hip_bf16.h>
#include <hip/hip_cooperative_groups.h>

namespace cg = cooperative_groups;

#define N_NODES 100000
#define N_FEATS 512
#define HIDDEN 64
#define NUM_SAMPLES 5
#define NUM_CLASSES 16
#define BATCH 16384

typedef __attribute__((ext_vector_type(8))) short bf16x8;
typedef __attribute__((ext_vector_type(8))) unsigned short u16x8;
typedef __attribute__((ext_vector_type(4))) float f32x4;

static __device__ __forceinline__ float bf2f(unsigned short s) {
    unsigned int u = ((unsigned int)s) << 16;
    return __builtin_bit_cast(float, u);
}
static __device__ __forceinline__ short f2bf(float v) {
    __hip_bfloat16 b = __float2bfloat16(v);
    return *reinterpret_cast<short*>(&b);
}
static __device__ __forceinline__ int clampi(int v) {
    return ((unsigned)v < (unsigned)N_NODES) ? v : 0;
}

// ---------------------------------------------------------------------------
// Fused cooperative kernel: phase0 prep -> phase1 pq_gemm -> phase2 h1_combine
// -> phase3 layer2_cls, separated by grid.sync(). All phases grid-stride so
// any co-resident grid size is correct. LDS (32KB) reused across phases.
// ---------------------------------------------------------------------------
__global__ __launch_bounds__(256, 4) void fused(
    const float* __restrict__ feat, const float* __restrict__ w1f,
    const float* __restrict__ w2, const float* __restrict__ wcls,
    const int* __restrict__ nodes_i32, const int* __restrict__ neigh_idx,
    short* __restrict__ w1p, short* __restrict__ PQ, float* __restrict__ out) {
    cg::grid_group grid = cg::this_grid();
    __shared__ __align__(16) char smem[32768];

    const int wave = threadIdx.x >> 6;
    const int lane = threadIdx.x & 63;
    const int quad = lane >> 4;
    const int l16  = lane & 15;
    const int gsz  = gridDim.x * 256;

    // ---- phase 0: pack w1 [64][1024] fp32 -> bf16 MFMA-fragment order ----
    for (int t = blockIdx.x * 256 + threadIdx.x; t < 64 * 1024; t += gsz) {
        const int j = t & 7;
        const int pl = (t >> 3) & 63;
        const int nb = (t >> 9) & 7;
        const int kk = t >> 12;
        const int pl16 = pl & 15, pquad = pl >> 4;
        const int cn = nb * 16 + pl16;
        const int h = cn & 63, part = cn >> 6;
        w1p[t] = f2bf(w1f[h * 1024 + part * 512 + kk * 32 + pquad * 8 + j]);
    }
    __threadfence();
    grid.sync();

    // ---- phase 1: PQ[n][c] = feat @ [W1a|W1b]^T (bf16 out) ----
    {
        short* at = reinterpret_cast<short*>(smem) + wave * 16 * 256;  // wave-private [16][256]
        const int nTiles = (N_NODES + 63) / 64;
        for (int tile = blockIdx.x; tile < nTiles; tile += gridDim.x) {
            const int r0 = tile * 64 + wave * 16;

            f32x4 acc[8];
#pragma unroll
            for (int i = 0; i < 8; i++) acc[i] = (f32x4){0.f, 0.f, 0.f, 0.f};

            for (int kh = 0; kh < 2; kh++) {  // two K-halves of 256
                f32x4 buf[2][4];

#define ISSUE_GRP(g, slot)                                                        \
                {                                                                 \
                    _Pragma("unroll")                                             \
                    for (int j = 0; j < 4; j++) {                                 \
                        int rA = r0 + (g) * 4 + j;                                \
                        if (rA >= N_NODES) rA = N_NODES - 1;                      \
                        buf[slot][j] = *reinterpret_cast<const f32x4*>(           \
                            feat + (size_t)rA * N_FEATS + kh * 256 + lane * 4);   \
                    }                                                             \
                }

                ISSUE_GRP(0, 0)
                ISSUE_GRP(1, 1)
#pragma unroll
                for (int g = 0; g < 4; g++) {
                    const int slot = g & 1;
#pragma unroll
                    for (int j = 0; j < 4; j++) {
                        const int r = g * 4 + j;
                        f32x4 v = buf[slot][j];
                        unsigned long long pk =
                              (unsigned long long)(unsigned short)f2bf(v[0])
                            | ((unsigned long long)(unsigned short)f2bf(v[1]) << 16)
                            | ((unsigned long long)(unsigned short)f2bf(v[2]) << 32)
                            | ((unsigned long long)(unsigned short)f2bf(v[3]) << 48);
                        const int chunk = (lane >> 1) ^ (r & 7);  // T2 swizzle
                        *reinterpret_cast<unsigned long long*>(
                            at + r * 256 + chunk * 8 + (lane & 1) * 4) = pk;
                    }
                    if (g < 2) ISSUE_GRP(g + 2, slot)
                }
#undef ISSUE_GRP

#pragma unroll
                for (int kk = 0; kk < 8; kk++) {
                    const int chunk = kk * 4 + quad;
                    const int cs = chunk ^ (l16 & 7);
                    bf16x8 afrag = *reinterpret_cast<const bf16x8*>(at + l16 * 256 + cs * 8);
                    const short* bk = w1p + (size_t)(kh * 8 + kk) * 4096 + lane * 8;
#pragma unroll
                    for (int nb = 0; nb < 8; nb++) {
                        bf16x8 bfrag = *reinterpret_cast<const bf16x8*>(bk + nb * 512);
                        acc[nb] = __builtin_amdgcn_mfma_f32_16x16x32_bf16(afrag, bfrag, acc[nb], 0, 0, 0);
                    }
                }
            }

            // C/D layout (16x16x32): col(N) = lane&15 -> cn, row(M) = quad*4 + reg
#pragma unroll
            for (int nb = 0; nb < 8; nb++) {
                const int cn = nb * 16 + l16;
#pragma unroll
                for (int r = 0; r < 4; r++) {
                    const int row = r0 + quad * 4 + r;
                    if (row < N_NODES) PQ[(size_t)row * 128 + cn] = f2bf(acc[nb][r]);
                }
            }
        }
    }
    __threadfence();
    grid.sync();

    // ---- phase 2: h1[n][h] = relu(P + 0.2*sum_s Q[neigh]) in-place (cols 0..63) ----
    for (int t = blockIdx.x * 256 + threadIdx.x; t < N_NODES * 8; t += gsz) {
        const int n = t >> 3;
        const int sub = t & 7;
        u16x8 pv = *reinterpret_cast<const u16x8*>(PQ + (size_t)n * 128 + sub * 8);
        float s[8];
#pragma unroll
        for (int j = 0; j < 8; j++) s[j] = 0.f;
#pragma unroll
        for (int i = 0; i < NUM_SAMPLES; i++) {
            const int ni = clampi(neigh_idx[n * NUM_SAMPLES + i]);
            u16x8 qv = *reinterpret_cast<const u16x8*>(PQ + (size_t)ni * 128 + 64 + sub * 8);
#pragma unroll
            for (int j = 0; j < 8; j++) s[j] += bf2f(qv[j]);
        }
        u16x8 ov;
#pragma unroll
        for (int j = 0; j < 8; j++) {
            float v = bf2f(pv[j]) + 0.2f * s[j];
            v = v > 0.f ? v : 0.f;
            ov[j] = (unsigned short)f2bf(v);
        }
        *reinterpret_cast<u16x8*>(PQ + (size_t)n * 128 + sub * 8) = ov;
    }
    __threadfence();
    grid.sync();

    // ---- phase 3: layer2 + classifier ----
    {
        float (*gbuf)[128] = reinterpret_cast<float (*)[128]>(smem);
        float (*h2buf)[64] = reinterpret_cast<float (*)[64]>(smem + 16 * 128 * 4);
        // nodes dtype detection: int64 iff all odd int32 words (first 64) are 0
        const int odd = nodes_i32[2 * lane + 1];
        const int is64 = (__ballot(odd != 0) == 0ull) ? 1 : 0;

        for (int grp = blockIdx.x; grp < BATCH / 16; grp += gridDim.x) {
            const int b0 = grp * 16;
#pragma unroll
            for (int it = 0; it < 4; it++) {
                const int item = wave * 4 + it;
                const int b = b0 + item;
                const int node = clampi(nodes_i32[is64 ? 2 * b : b]);
                float selfv = bf2f((unsigned short)PQ[(size_t)node * 128 + lane]);
                float ns = 0.f;
#pragma unroll
                for (int s = 0; s < NUM_SAMPLES; s++) {
                    const int ni = clampi(neigh_idx[node * NUM_SAMPLES + s]);
                    ns += bf2f((unsigned short)PQ[(size_t)ni * 128 + lane]);
                }
                gbuf[item][lane] = selfv;
                gbuf[item][64 + lane] = 0.2f * ns;
            }
            __syncthreads();

            float acc[4] = {0.f, 0.f, 0.f, 0.f};
            const f32x4* w2r = reinterpret_cast<const f32x4*>(w2 + lane * 128);
#pragma unroll 8
            for (int k = 0; k < 32; k++) {
                f32x4 w = w2r[k];
#pragma unroll
                for (int it = 0; it < 4; it++) {
                    f32x4 g = *reinterpret_cast<const f32x4*>(&gbuf[wave * 4 + it][k * 4]);
                    acc[it] += g[0] * w[0] + g[1] * w[1] + g[2] * w[2] + g[3] * w[3];
                }
            }
#pragma unroll
            for (int it = 0; it < 4; it++) {
                float h2 = acc[it] > 0.f ? acc[it] : 0.f;
                h2buf[wave * 4 + it][lane] = h2;
            }
            __syncthreads();

            if (lane < NUM_CLASSES) {
                const f32x4* wcr = reinterpret_cast<const f32x4*>(wcls + lane * 64);
#pragma unroll
                for (int it = 0; it < 4; it++) {
                    const int item = wave * 4 + it;
                    const f32x4* hr = reinterpret_cast<const f32x4*>(&h2buf[item][0]);
                    float o = 0.f;
#pragma unroll
                    for (int k = 0; k < 16; k++) {
                        f32x4 h = hr[k], w = wcr[k];
                        o += h[0] * w[0] + h[1] * w[1] + h[2] * w[2] + h[3] * w[3];
                    }
                    out[(size_t)(b0 + item) * NUM_CLASSES + lane] = o;
                }
            }
            __syncthreads();  // before next grp overwrites gbuf/h2buf
        }
    }
}

// ---------------------------------------------------------------------------
// Fallback path (non-cooperative), identical to the previous 4-kernel version.
// Used only if hipLaunchCooperativeKernel is rejected (e.g. by graph capture).
// ---------------------------------------------------------------------------
__global__ __launch_bounds__(256) void prep(const float* __restrict__ w1f,
                                            short* __restrict__ w1p,
                                            const int* __restrict__ nodes_i32,
                                            int* __restrict__ flag) {
    const int t = blockIdx.x * 256 + threadIdx.x;
    if (t < 64 * 1024) {
        const int j = t & 7;
        const int lane = (t >> 3) & 63;
        const int nb = (t >> 9) & 7;
        const int kk = t >> 12;
        const int l16 = lane & 15, quad = lane >> 4;
        const int cn = nb * 16 + l16;
        const int h = cn & 63, part = cn >> 6;
        w1p[t] = f2bf(w1f[h * 1024 + part * 512 + kk * 32 + quad * 8 + j]);
    }
    if (blockIdx.x == 0 && threadIdx.x == 0) {
        int odd_nonzero = 0;
        for (int i = 0; i < 64; i++)
            if (nodes_i32[2 * i + 1] != 0) odd_nonzero++;
        *flag = (odd_nonzero == 0) ? 1 : 0;
    }
}

__global__ __launch_bounds__(256) void pq_gemm(const float* __restrict__ feat,
                                               const short* __restrict__ w1p,
                                               short* __restrict__ PQ) {
    __shared__ __align__(16) short atile[4][16][256];
    const int wave = threadIdx.x >> 6;
    const int lane = threadIdx.x & 63;
    const int quad = lane >> 4;
    const int l16  = lane & 15;
    const int r0   = blockIdx.x * 64 + wave * 16;
    short* at = &atile[wave][0][0];

    f32x4 acc[8];
#pragma unroll
    for (int i = 0; i < 8; i++) acc[i] = (f32x4){0.f, 0.f, 0.f, 0.f};

    for (int kh = 0; kh < 2; kh++) {
        f32x4 buf[2][4];
#define ISSUE_GRP(g, slot)                                                        \
        {                                                                         \
            _Pragma("unroll")                                                     \
            for (int j = 0; j < 4; j++) {                                         \
                int rA = r0 + (g) * 4 + j;                                        \
                if (rA >= N_NODES) rA = N_NODES - 1;                              \
                buf[slot][j] = *reinterpret_cast<const f32x4*>(                   \
                    feat + (size_t)rA * N_FEATS + kh * 256 + lane * 4);           \
            }                                                                     \
        }
        ISSUE_GRP(0, 0)
        ISSUE_GRP(1, 1)
#pragma unroll
        for (int g = 0; g < 4; g++) {
            const int slot = g & 1;
#pragma unroll
            for (int j = 0; j < 4; j++) {
                const int r = g * 4 + j;
                f32x4 v = buf[slot][j];
                unsigned long long pk =
                      (unsigned long long)(unsigned short)f2bf(v[0])
                    | ((unsigned long long)(unsigned short)f2bf(v[1]) << 16)
                    | ((unsigned long long)(unsigned short)f2bf(v[2]) << 32)
                    | ((unsigned long long)(unsigned short)f2bf(v[3]) << 48);
                const int chunk = (lane >> 1) ^ (r & 7);
                *reinterpret_cast<unsigned long long*>(
                    at + r * 256 + chunk * 8 + (lane & 1) * 4) = pk;
            }
            if (g < 2) ISSUE_GRP(g + 2, slot)
        }
#undef ISSUE_GRP
#pragma unroll
        for (int kk = 0; kk < 8; kk++) {
            const int chunk = kk * 4 + quad;
            const int cs = chunk ^ (l16 & 7);
            bf16x8 afrag = *reinterpret_cast<const bf16x8*>(at + l16 * 256 + cs * 8);
            const short* bk = w1p + (size_t)(kh * 8 + kk) * 4096 + lane * 8;
#pragma unroll
            for (int nb = 0; nb < 8; nb++) {
                bf16x8 bfrag = *reinterpret_cast<const bf16x8*>(bk + nb * 512);
                acc[nb] = __builtin_amdgcn_mfma_f32_16x16x32_bf16(afrag, bfrag, acc[nb], 0, 0, 0);
            }
        }
    }
#pragma unroll
    for (int nb = 0; nb < 8; nb++) {
        const int cn = nb * 16 + l16;
#pragma unroll
        for (int r = 0; r < 4; r++) {
            const int row = r0 + quad * 4 + r;
            if (row < N_NODES) PQ[(size_t)row * 128 + cn] = f2bf(acc[nb][r]);
        }
    }
}

__global__ __launch_bounds__(256) void h1_combine(short* __restrict__ PQ,
                                                  const int* __restrict__ neigh_idx) {
    const int t = blockIdx.x * 256 + threadIdx.x;
    const int n = t >> 3;
    const int sub = t & 7;
    if (n >= N_NODES) return;
    u16x8 pv = *reinterpret_cast<const u16x8*>(PQ + (size_t)n * 128 + sub * 8);
    float s[8];
#pragma unroll
    for (int j = 0; j < 8; j++) s[j] = 0.f;
#pragma unroll
    for (int i = 0; i < NUM_SAMPLES; i++) {
        const int ni = clampi(neigh_idx[n * NUM_SAMPLES + i]);
        u16x8 qv = *reinterpret_cast<const u16x8*>(PQ + (size_t)ni * 128 + 64 + sub * 8);
#pragma unroll
        for (int j = 0; j < 8; j++) s[j] += bf2f(qv[j]);
    }
    u16x8 ov;
#pragma unroll
    for (int j = 0; j < 8; j++) {
        float v = bf2f(pv[j]) + 0.2f * s[j];
        v = v > 0.f ? v : 0.f;
        ov[j] = (unsigned short)f2bf(v);
    }
    *reinterpret_cast<u16x8*>(PQ + (size_t)n * 128 + sub * 8) = ov;
}

__global__ __launch_bounds__(256) void layer2_cls(const short* __restrict__ PQ,
                                                  const int* __restrict__ nodes_i32,
                                                  const int* __restrict__ neigh_idx,
                                                  const float* __restrict__ w2,
                                                  const float* __restrict__ wcls,
                                                  const int* __restrict__ flag,
                                                  float* __restrict__ out) {
    __shared__ float gbuf[16][128];
    __shared__ float h2buf[16][64];
    const int wave = threadIdx.x >> 6;
    const int lane = threadIdx.x & 63;
    const int is64 = *flag;
    const int b0 = blockIdx.x * 16;
#pragma unroll
    for (int it = 0; it < 4; it++) {
        const int item = wave * 4 + it;
        const int b = b0 + item;
        const int node = clampi(nodes_i32[is64 ? 2 * b : b]);
        float selfv = bf2f((unsigned short)PQ[(size_t)node * 128 + lane]);
        float ns = 0.f;
#pragma unroll
        for (int s = 0; s < NUM_SAMPLES; s++) {
            const int ni = clampi(neigh_idx[node * NUM_SAMPLES + s]);
            ns += bf2f((unsigned short)PQ[(size_t)ni * 128 + lane]);
        }
        gbuf[item][lane] = selfv;
        gbuf[item][64 + lane] = 0.2f * ns;
    }
    __syncthreads();
    float acc[4] = {0.f, 0.f, 0.f, 0.f};
    const f32x4* w2r = reinterpret_cast<const f32x4*>(w2 + lane * 128);
#pragma unroll 8
    for (int k = 0; k < 32; k++) {
        f32x4 w = w2r[k];
#pragma unroll
        for (int it = 0; it < 4; it++) {
            f32x4 g = *reinterpret_cast<const f32x4*>(&gbuf[wave * 4 + it][k * 4]);
            acc[it] += g[0] * w[0] + g[1] * w[1] + g[2] * w[2] + g[3] * w[3];
        }
    }
#pragma unroll
    for (int it = 0; it < 4; it++) {
        float h2 = acc[it] > 0.f ? acc[it] : 0.f;
        h2buf[wave * 4 + it][lane] = h2;
    }
    __syncthreads();
    if (lane < NUM_CLASSES) {
        const f32x4* wcr = reinterpret_cast<const f32x4*>(wcls + lane * 64);
#pragma unroll
        for (int it = 0; it < 4; it++) {
            const int item = wave * 4 + it;
            const f32x4* hr = reinterpret_cast<const f32x4*>(&h2buf[item][0]);
            float o = 0.f;
#pragma unroll
            for (int k = 0; k < 16; k++) {
                f32x4 h = hr[k], w = wcr[k];
                o += h[0] * w[0] + h[1] * w[1] + h[2] * w[2] + h[3] * w[3];
            }
            out[(size_t)(b0 + item) * NUM_CLASSES + lane] = o;
        }
    }
}

extern "C" void kernel_launch(void* const* d_in, const int* in_sizes, int n_in,
                              void* d_out, int out_size, void* d_ws, size_t ws_size,
                              hipStream_t stream) {
    const float* feat = nullptr;      // 100000*512  = 51,200,000
    const float* w1 = nullptr;        // 64*1024     = 65,536
    const float* w2 = nullptr;        // 64*128      = 8,192
    const float* wcls = nullptr;      // 16*64       = 1,024
    const int* nodes = nullptr;       // 16,384
    const int* neigh_idx = nullptr;   // 100000*5    = 500,000
    for (int i = 0; i < n_in; i++) {
        switch (in_sizes[i]) {
            case 51200000: feat = (const float*)d_in[i]; break;
            case 65536:    w1 = (const float*)d_in[i]; break;
            case 8192:     w2 = (const float*)d_in[i]; break;
            case 1024:     wcls = (const float*)d_in[i]; break;
            case 16384:    nodes = (const int*)d_in[i]; break;
            case 500000:   neigh_idx = (const int*)d_in[i]; break;
            default: break;
        }
    }
    float* out = (float*)d_out;

    int* flag = (int*)d_ws;
    short* w1p = (short*)((char*)d_ws + 256);
    short* PQ  = (short*)((char*)d_ws + 256 + 64 * 1024 * sizeof(short));

    // Grid sized to guaranteed co-residency (cooperative requirement).
    static int gridBlocks = 0;
    if (gridBlocks == 0) {
        int bpc = 0;
        hipOccupancyMaxActiveBlocksPerMultiprocessor(&bpc, (const void*)fused, 256, 0);
        if (bpc < 1) bpc = 1;
        int dev = 0, cus = 0;
        hipGetDevice(&dev);
        hipDeviceGetAttribute(&cus, hipDeviceAttributeMultiprocessorCount, dev);
        if (cus <= 0) cus = 256;
        long total = (long)bpc * cus;
        const long maxUseful = (N_NODES + 63) / 64;  // 1564
        gridBlocks = (int)(total > maxUseful ? maxUseful : total);
    }

    void* args[] = {(void*)&feat, (void*)&w1, (void*)&w2, (void*)&wcls,
                    (void*)&nodes, (void*)&neigh_idx, (void*)&w1p, (void*)&PQ,
                    (void*)&out};
    hipError_t err = hipLaunchCooperativeKernel((const void*)fused, dim3(gridBlocks),
                                                dim3(256), args, 0, stream);
    if (err != hipSuccess) {
        // Fallback: original 4-kernel pipeline.
        prep<<<256, 256, 0, stream>>>(w1, w1p, nodes, flag);
        pq_gemm<<<(N_NODES + 63) / 64, 256, 0, stream>>>(feat, w1p, PQ);
        h1_combine<<<(N_NODES * 8 + 255) / 256, 256, 0, stream>>>(PQ, neigh_idx);
        layer2_cls<<<BATCH / 16, 256, 0, stream>>>(PQ, nodes, neigh_idx, w2, wcls, flag, out);
    }
}

// Round 3
// 466.181 us; speedup vs baseline: 1.8824x; 1.8824x over previous
//
#include <hip/hip_runtime.h>
#include <hip/hip_bf16.h>

#define N_NODES 100000
#define N_FEATS 512
#define HIDDEN 64
#define NUM_SAMPLES 5
#define NUM_CLASSES 16
#define BATCH 16384

typedef __attribute__((ext_vector_type(8))) short bf16x8;
typedef __attribute__((ext_vector_type(8))) unsigned short u16x8;
typedef __attribute__((ext_vector_type(4))) float f32x4;

static __device__ __forceinline__ float bf2f(unsigned short s) {
    unsigned int u = ((unsigned int)s) << 16;
    return __builtin_bit_cast(float, u);
}
static __device__ __forceinline__ short f2bf(float v) {
    __hip_bfloat16 b = __float2bfloat16(v);
    return *reinterpret_cast<short*>(&b);
}
static __device__ __forceinline__ int clampi(int v) {
    return ((unsigned)v < (unsigned)N_NODES) ? v : 0;
}

// prep: (a) repack w1 [64][1024] fp32 into bf16 MFMA-fragment order:
// w1p[((kk*8 + nb)*64 + lane)*8 + j] = w1[h][part*512 + kk*32 + quad*8 + j]
// (b) detect whether `nodes` is int64 (odd int32 words all zero).
__global__ __launch_bounds__(256) void prep(const float* __restrict__ w1f,
                                            short* __restrict__ w1p,
                                            const int* __restrict__ nodes_i32,
                                            int* __restrict__ flag) {
    const int t = blockIdx.x * 256 + threadIdx.x;  // 0..65535
    if (t < 64 * 1024) {
        const int j = t & 7;
        const int lane = (t >> 3) & 63;
        const int nb = (t >> 9) & 7;
        const int kk = t >> 12;
        const int l16 = lane & 15, quad = lane >> 4;
        const int cn = nb * 16 + l16;
        const int h = cn & 63, part = cn >> 6;
        w1p[t] = f2bf(w1f[h * 1024 + part * 512 + kk * 32 + quad * 8 + j]);
    }
    if (blockIdx.x == 0 && threadIdx.x == 0) {
        int odd_nonzero = 0;
        for (int i = 0; i < 64; i++)
            if (nodes_i32[2 * i + 1] != 0) odd_nonzero++;
        *flag = (odd_nonzero == 0) ? 1 : 0;  // 1 => nodes is int64
    }
}

// Kernel A: PQ[n][c] (bf16): c<64 -> feat @ W1a^T ; c in [64,128) -> feat @ W1b^T
// Wave-private reg->LDS staging (contiguous 1KB global loads, bf16 convert at
// staging, T2 XOR-swizzled LDS, 2-deep load pipeline). Idempotent.
__global__ __launch_bounds__(256) void pq_gemm(const float* __restrict__ feat,
                                               const short* __restrict__ w1p,
                                               short* __restrict__ PQ) {
    __shared__ __align__(16) short atile[4][16][256];
    const int wave = threadIdx.x >> 6;
    const int lane = threadIdx.x & 63;
    const int quad = lane >> 4;
    const int l16  = lane & 15;
    const int r0   = blockIdx.x * 64 + wave * 16;
    short* at = &atile[wave][0][0];

    f32x4 acc[8];
#pragma unroll
    for (int i = 0; i < 8; i++) acc[i] = (f32x4){0.f, 0.f, 0.f, 0.f};

    for (int kh = 0; kh < 2; kh++) {  // two K-halves of 256
        f32x4 buf[2][4];
#define ISSUE_GRP(g, slot)                                                        \
        {                                                                         \
            _Pragma("unroll")                                                     \
            for (int j = 0; j < 4; j++) {                                         \
                int rA = r0 + (g) * 4 + j;                                        \
                if (rA >= N_NODES) rA = N_NODES - 1;                              \
                buf[slot][j] = *reinterpret_cast<const f32x4*>(                   \
                    feat + (size_t)rA * N_FEATS + kh * 256 + lane * 4);           \
            }                                                                     \
        }
        ISSUE_GRP(0, 0)
        ISSUE_GRP(1, 1)
#pragma unroll
        for (int g = 0; g < 4; g++) {
            const int slot = g & 1;
#pragma unroll
            for (int j = 0; j < 4; j++) {
                const int r = g * 4 + j;
                f32x4 v = buf[slot][j];
                unsigned long long pk =
                      (unsigned long long)(unsigned short)f2bf(v[0])
                    | ((unsigned long long)(unsigned short)f2bf(v[1]) << 16)
                    | ((unsigned long long)(unsigned short)f2bf(v[2]) << 32)
                    | ((unsigned long long)(unsigned short)f2bf(v[3]) << 48);
                const int chunk = (lane >> 1) ^ (r & 7);  // T2 swizzle
                *reinterpret_cast<unsigned long long*>(
                    at + r * 256 + chunk * 8 + (lane & 1) * 4) = pk;
            }
            if (g < 2) ISSUE_GRP(g + 2, slot)
        }
#undef ISSUE_GRP
#pragma unroll
        for (int kk = 0; kk < 8; kk++) {
            const int chunk = kk * 4 + quad;
            const int cs = chunk ^ (l16 & 7);
            bf16x8 afrag = *reinterpret_cast<const bf16x8*>(at + l16 * 256 + cs * 8);
            const short* bk = w1p + (size_t)(kh * 8 + kk) * 4096 + lane * 8;
#pragma unroll
            for (int nb = 0; nb < 8; nb++) {
                bf16x8 bfrag = *reinterpret_cast<const bf16x8*>(bk + nb * 512);
                acc[nb] = __builtin_amdgcn_mfma_f32_16x16x32_bf16(afrag, bfrag, acc[nb], 0, 0, 0);
            }
        }
    }
    // C/D layout (16x16x32): col(N) = lane&15 -> cn, row(M) = quad*4 + reg
#pragma unroll
    for (int nb = 0; nb < 8; nb++) {
        const int cn = nb * 16 + l16;
#pragma unroll
        for (int r = 0; r < 4; r++) {
            const int row = r0 + quad * 4 + r;
            if (row < N_NODES) PQ[(size_t)row * 128 + cn] = f2bf(acc[nb][r]);
        }
    }
}

// Kernel B: h1[n][h] = relu(P[n][h] + 0.2*sum_s Q[neigh[n][s]][h]) -> H1[n][64]
// (separate output buffer: reads PQ only, writes H1 only -> idempotent).
// 8 threads per node, 16B per thread.
__global__ __launch_bounds__(256) void h1_combine(const short* __restrict__ PQ,
                                                  const int* __restrict__ neigh_idx,
                                                  short* __restrict__ H1) {
    const int t = blockIdx.x * 256 + threadIdx.x;
    const int n = t >> 3;
    const int sub = t & 7;
    if (n >= N_NODES) return;

    u16x8 pv = *reinterpret_cast<const u16x8*>(PQ + (size_t)n * 128 + sub * 8);
    float s[8];
#pragma unroll
    for (int j = 0; j < 8; j++) s[j] = 0.f;
#pragma unroll
    for (int i = 0; i < NUM_SAMPLES; i++) {
        const int ni = clampi(neigh_idx[n * NUM_SAMPLES + i]);
        u16x8 qv = *reinterpret_cast<const u16x8*>(PQ + (size_t)ni * 128 + 64 + sub * 8);
#pragma unroll
        for (int j = 0; j < 8; j++) s[j] += bf2f(qv[j]);
    }
    u16x8 ov;
#pragma unroll
    for (int j = 0; j < 8; j++) {
        float v = bf2f(pv[j]) + 0.2f * s[j];
        v = v > 0.f ? v : 0.f;
        ov[j] = (unsigned short)f2bf(v);
    }
    *reinterpret_cast<u16x8*>(H1 + (size_t)n * 64 + sub * 8) = ov;
}

// Kernel C: 16 batch items per block (4 per wave). g = concat(h1[node],
// 0.2*sum_s h1[neigh[node][s]]); h2 = relu(g @ w2^T); out = h2 @ wcls^T (fp32).
// Reads H1 rows (64 bf16 = 128B, fully-used lines). Idempotent.
__global__ __launch_bounds__(256) void layer2_cls(const short* __restrict__ H1,
                                                  const int* __restrict__ nodes_i32,
                                                  const int* __restrict__ neigh_idx,
                                                  const float* __restrict__ w2,
                                                  const float* __restrict__ wcls,
                                                  const int* __restrict__ flag,
                                                  float* __restrict__ out) {
    __shared__ float gbuf[16][128];
    __shared__ float h2buf[16][64];
    const int wave = threadIdx.x >> 6;
    const int lane = threadIdx.x & 63;
    const int is64 = *flag;
    const int b0 = blockIdx.x * 16;

#pragma unroll
    for (int it = 0; it < 4; it++) {
        const int item = wave * 4 + it;
        const int b = b0 + item;
        const int node = clampi(nodes_i32[is64 ? 2 * b : b]);
        float selfv = bf2f((unsigned short)H1[(size_t)node * 64 + lane]);
        float ns = 0.f;
#pragma unroll
        for (int s = 0; s < NUM_SAMPLES; s++) {
            const int ni = clampi(neigh_idx[node * NUM_SAMPLES + s]);
            ns += bf2f((unsigned short)H1[(size_t)ni * 64 + lane]);
        }
        gbuf[item][lane] = selfv;
        gbuf[item][64 + lane] = 0.2f * ns;
    }
    __syncthreads();

    float acc[4] = {0.f, 0.f, 0.f, 0.f};
    const f32x4* w2r = reinterpret_cast<const f32x4*>(w2 + lane * 128);
#pragma unroll 8
    for (int k = 0; k < 32; k++) {
        f32x4 w = w2r[k];
#pragma unroll
        for (int it = 0; it < 4; it++) {
            f32x4 g = *reinterpret_cast<const f32x4*>(&gbuf[wave * 4 + it][k * 4]);
            acc[it] += g[0] * w[0] + g[1] * w[1] + g[2] * w[2] + g[3] * w[3];
        }
    }
#pragma unroll
    for (int it = 0; it < 4; it++) {
        float h2 = acc[it] > 0.f ? acc[it] : 0.f;
        h2buf[wave * 4 + it][lane] = h2;
    }
    __syncthreads();

    if (lane < NUM_CLASSES) {
        const f32x4* wcr = reinterpret_cast<const f32x4*>(wcls + lane * 64);
#pragma unroll
        for (int it = 0; it < 4; it++) {
            const int item = wave * 4 + it;
            const f32x4* hr = reinterpret_cast<const f32x4*>(&h2buf[item][0]);
            float o = 0.f;
#pragma unroll
            for (int k = 0; k < 16; k++) {
                f32x4 h = hr[k], w = wcr[k];
                o += h[0] * w[0] + h[1] * w[1] + h[2] * w[2] + h[3] * w[3];
            }
            out[(size_t)(b0 + item) * NUM_CLASSES + lane] = o;
        }
    }
}

extern "C" void kernel_launch(void* const* d_in, const int* in_sizes, int n_in,
                              void* d_out, int out_size, void* d_ws, size_t ws_size,
                              hipStream_t stream) {
    const float* feat = nullptr;      // 100000*512  = 51,200,000
    const float* w1 = nullptr;        // 64*1024     = 65,536
    const float* w2 = nullptr;        // 64*128      = 8,192
    const float* wcls = nullptr;      // 16*64       = 1,024
    const int* nodes = nullptr;       // 16,384
    const int* neigh_idx = nullptr;   // 100000*5    = 500,000
    for (int i = 0; i < n_in; i++) {
        switch (in_sizes[i]) {
            case 51200000: feat = (const float*)d_in[i]; break;
            case 65536:    w1 = (const float*)d_in[i]; break;
            case 8192:     w2 = (const float*)d_in[i]; break;
            case 1024:     wcls = (const float*)d_in[i]; break;
            case 16384:    nodes = (const int*)d_in[i]; break;
            case 500000:   neigh_idx = (const int*)d_in[i]; break;
            default: break;
        }
    }
    float* out = (float*)d_out;  // [16384,16] fp32

    // ws layout: [0..4) nodes-dtype flag; [256..) packed w1 bf16 (131072 B);
    // PQ bf16 [100000][128] (25.6 MB); H1 bf16 [100000][64] (12.8 MB).
    int* flag = (int*)d_ws;
    short* w1p = (short*)((char*)d_ws + 256);
    short* PQ  = (short*)((char*)d_ws + 256 + 131072);
    short* H1  = (short*)((char*)d_ws + 256 + 131072 + (size_t)N_NODES * 128 * 2);

    // ATTRIBUTION EXPERIMENT: every stage is idempotent; the heavy ones are
    // dispatched TWICE. dur - baseline(360) ~= warm cost(pq + h1 + l2).
    prep<<<256, 256, 0, stream>>>(w1, w1p, nodes, flag);
    pq_gemm<<<(N_NODES + 63) / 64, 256, 0, stream>>>(feat, w1p, PQ);
    pq_gemm<<<(N_NODES + 63) / 64, 256, 0, stream>>>(feat, w1p, PQ);
    h1_combine<<<(N_NODES * 8 + 255) / 256, 256, 0, stream>>>(PQ, neigh_idx, H1);
    h1_combine<<<(N_NODES * 8 + 255) / 256, 256, 0, stream>>>(PQ, neigh_idx, H1);
    layer2_cls<<<BATCH / 16, 256, 0, stream>>>(H1, nodes, neigh_idx, w2, wcls, flag, out);
    layer2_cls<<<BATCH / 16, 256, 0, stream>>>(H1, nodes, neigh_idx, w2, wcls, flag, out);
}

// Round 4
// 337.060 us; speedup vs baseline: 2.6036x; 1.3831x over previous
//
#include <hip/hip_runtime.h>
#include <hip/hip_bf16.h>

#define N_NODES 100000
#define N_FEATS 512
#define HIDDEN 64
#define NUM_SAMPLES 5
#define NUM_CLASSES 16
#define BATCH 16384
#define N_TILES (N_NODES / 16)  // 6250 exactly

typedef __attribute__((ext_vector_type(8))) short bf16x8;
typedef __attribute__((ext_vector_type(8))) unsigned short u16x8;
typedef __attribute__((ext_vector_type(4))) float f32x4;

static __device__ __forceinline__ float bf2f(unsigned short s) {
    unsigned int u = ((unsigned int)s) << 16;
    return __builtin_bit_cast(float, u);
}
static __device__ __forceinline__ short f2bf(float v) {
    __hip_bfloat16 b = __float2bfloat16(v);
    return *reinterpret_cast<short*>(&b);
}
static __device__ __forceinline__ int clampi(int v) {
    return ((unsigned)v < (unsigned)N_NODES) ? v : 0;
}

// prep: (a) repack w1 [64][1024] fp32 into bf16 MFMA-fragment order:
// w1p[((kk*8 + nb)*64 + lane)*8 + j] = w1[h][part*512 + kk*32 + quad*8 + j]
// (b) detect whether `nodes` is int64 (odd int32 words all zero).
__global__ __launch_bounds__(256) void prep(const float* __restrict__ w1f,
                                            short* __restrict__ w1p,
                                            const int* __restrict__ nodes_i32,
                                            int* __restrict__ flag) {
    const int t = blockIdx.x * 256 + threadIdx.x;  // 0..65535
    if (t < 64 * 1024) {
        const int j = t & 7;
        const int lane = (t >> 3) & 63;
        const int nb = (t >> 9) & 7;
        const int kk = t >> 12;
        const int l16 = lane & 15, quad = lane >> 4;
        const int cn = nb * 16 + l16;
        const int h = cn & 63, part = cn >> 6;
        w1p[t] = f2bf(w1f[h * 1024 + part * 512 + kk * 32 + quad * 8 + j]);
    }
    if (blockIdx.x == 0 && threadIdx.x == 0) {
        int odd_nonzero = 0;
        for (int i = 0; i < 64; i++)
            if (nodes_i32[2 * i + 1] != 0) odd_nonzero++;
        *flag = (odd_nonzero == 0) ? 1 : 0;  // 1 => nodes is int64
    }
}

// Kernel A v3: PQ[n][c] = feat @ [W1a|W1b]^T (bf16 out).
// 512 threads = 8 waves; wave w owns output col-block nb=w (16 cols).
// B-slice (16 kk x bf16x8 = 64 VGPR) loaded ONCE per kernel -> B L2 traffic
// drops from ~800 MB (per-tile reload) to 64 MB (prologue only).
// A-tile [16 rows][512 K] bf16 staged cooperatively in LDS (T2 XOR swizzle,
// conflict-free b128 reads), shared by all 8 waves. 2 barriers/tile; next
// tile's global loads issued before the ready-barrier.
__global__ __launch_bounds__(512) void pq_gemm(const float* __restrict__ feat,
                                               const short* __restrict__ w1p,
                                               short* __restrict__ PQ) {
    __shared__ __align__(16) short at[16 * 512];  // 16 KB A-tile, swizzled
    const int wave = threadIdx.x >> 6;   // 0..7 == nb
    const int lane = threadIdx.x & 63;
    const int quad = lane >> 4;
    const int l16  = lane & 15;
    const int tidr = threadIdx.x >> 5;   // staging row 0..15
    const int tids = threadIdx.x & 31;   // staging col-group 0..31

    // ---- B prologue: load this wave's nb-slice once (64 VGPRs) ----
    bf16x8 bfrag[16];
#pragma unroll
    for (int kk = 0; kk < 16; kk++)
        bfrag[kk] = *reinterpret_cast<const bf16x8*>(
            w1p + (size_t)kk * 4096 + wave * 512 + lane * 8);

    const int stride = gridDim.x;
    f32x4 ra[2][2];

#define LOAD_TILE(tt)                                                             \
    {                                                                             \
        const float* base = feat + (size_t)((tt) * 16 + tidr) * N_FEATS + tids * 8;\
        _Pragma("unroll")                                                         \
        for (int i = 0; i < 2; i++) {                                             \
            ra[i][0] = *reinterpret_cast<const f32x4*>(base + i * 256);           \
            ra[i][1] = *reinterpret_cast<const f32x4*>(base + i * 256 + 4);       \
        }                                                                         \
    }

    int t = blockIdx.x;
    if (t < N_TILES) LOAD_TILE(t)

    for (; t < N_TILES; t += stride) {
        __syncthreads();  // previous tile's A reads complete
        // stage A-tile from regs (convert once, b128 writes, T2 swizzle)
#pragma unroll
        for (int i = 0; i < 2; i++) {
            bf16x8 p;
#pragma unroll
            for (int j = 0; j < 4; j++) {
                p[j]     = f2bf(ra[i][0][j]);
                p[4 + j] = f2bf(ra[i][1][j]);
            }
            const int chunk = i * 32 + tids;           // 16B chunk in row
            const int cs = chunk ^ (tidr & 7);         // T2 swizzle
            *reinterpret_cast<bf16x8*>(at + tidr * 512 + cs * 8) = p;
        }
        // prefetch next tile (issued before the barrier; overlaps under TLP)
        const int tn = t + stride;
        if (tn < N_TILES) LOAD_TILE(tn)
        __syncthreads();  // A-tile ready

        f32x4 acc = (f32x4){0.f, 0.f, 0.f, 0.f};
#pragma unroll
        for (int kk = 0; kk < 16; kk++) {
            const int chunk = kk * 4 + quad;
            const int cs = chunk ^ (l16 & 7);
            bf16x8 afrag = *reinterpret_cast<const bf16x8*>(at + l16 * 512 + cs * 8);
            acc = __builtin_amdgcn_mfma_f32_16x16x32_bf16(afrag, bfrag[kk], acc, 0, 0, 0);
        }

        // C/D layout (16x16x32): col(N) = l16, row(M) = quad*4 + r
        const int cn = wave * 16 + l16;
#pragma unroll
        for (int r = 0; r < 4; r++) {
            const int row = t * 16 + quad * 4 + r;
            PQ[(size_t)row * 128 + cn] = f2bf(acc[r]);
        }
    }
#undef LOAD_TILE
}

// Kernel B: h1[n][h] = relu(P[n][h] + 0.2*sum_s Q[neigh[n][s]][h]) -> H1[n][64]
// (reads PQ only, writes H1 only). 8 threads per node, 16B per thread.
__global__ __launch_bounds__(256) void h1_combine(const short* __restrict__ PQ,
                                                  const int* __restrict__ neigh_idx,
                                                  short* __restrict__ H1) {
    const int t = blockIdx.x * 256 + threadIdx.x;
    const int n = t >> 3;
    const int sub = t & 7;
    if (n >= N_NODES) return;

    u16x8 pv = *reinterpret_cast<const u16x8*>(PQ + (size_t)n * 128 + sub * 8);
    float s[8];
#pragma unroll
    for (int j = 0; j < 8; j++) s[j] = 0.f;
#pragma unroll
    for (int i = 0; i < NUM_SAMPLES; i++) {
        const int ni = clampi(neigh_idx[n * NUM_SAMPLES + i]);
        u16x8 qv = *reinterpret_cast<const u16x8*>(PQ + (size_t)ni * 128 + 64 + sub * 8);
#pragma unroll
        for (int j = 0; j < 8; j++) s[j] += bf2f(qv[j]);
    }
    u16x8 ov;
#pragma unroll
    for (int j = 0; j < 8; j++) {
        float v = bf2f(pv[j]) + 0.2f * s[j];
        v = v > 0.f ? v : 0.f;
        ov[j] = (unsigned short)f2bf(v);
    }
    *reinterpret_cast<u16x8*>(H1 + (size_t)n * 64 + sub * 8) = ov;
}

// Kernel C: 16 batch items per block (4 per wave). g = concat(h1[node],
// 0.2*sum_s h1[neigh[node][s]]); h2 = relu(g @ w2^T); out = h2 @ wcls^T (fp32).
__global__ __launch_bounds__(256) void layer2_cls(const short* __restrict__ H1,
                                                  const int* __restrict__ nodes_i32,
                                                  const int* __restrict__ neigh_idx,
                                                  const float* __restrict__ w2,
                                                  const float* __restrict__ wcls,
                                                  const int* __restrict__ flag,
                                                  float* __restrict__ out) {
    __shared__ float gbuf[16][128];
    __shared__ float h2buf[16][64];
    const int wave = threadIdx.x >> 6;
    const int lane = threadIdx.x & 63;
    const int is64 = *flag;
    const int b0 = blockIdx.x * 16;

#pragma unroll
    for (int it = 0; it < 4; it++) {
        const int item = wave * 4 + it;
        const int b = b0 + item;
        const int node = clampi(nodes_i32[is64 ? 2 * b : b]);
        float selfv = bf2f((unsigned short)H1[(size_t)node * 64 + lane]);
        float ns = 0.f;
#pragma unroll
        for (int s = 0; s < NUM_SAMPLES; s++) {
            const int ni = clampi(neigh_idx[node * NUM_SAMPLES + s]);
            ns += bf2f((unsigned short)H1[(size_t)ni * 64 + lane]);
        }
        gbuf[item][lane] = selfv;
        gbuf[item][64 + lane] = 0.2f * ns;
    }
    __syncthreads();

    float acc[4] = {0.f, 0.f, 0.f, 0.f};
    const f32x4* w2r = reinterpret_cast<const f32x4*>(w2 + lane * 128);
#pragma unroll 8
    for (int k = 0; k < 32; k++) {
        f32x4 w = w2r[k];
#pragma unroll
        for (int it = 0; it < 4; it++) {
            f32x4 g = *reinterpret_cast<const f32x4*>(&gbuf[wave * 4 + it][k * 4]);
            acc[it] += g[0] * w[0] + g[1] * w[1] + g[2] * w[2] + g[3] * w[3];
        }
    }
#pragma unroll
    for (int it = 0; it < 4; it++) {
        float h2 = acc[it] > 0.f ? acc[it] : 0.f;
        h2buf[wave * 4 + it][lane] = h2;
    }
    __syncthreads();

    if (lane < NUM_CLASSES) {
        const f32x4* wcr = reinterpret_cast<const f32x4*>(wcls + lane * 64);
#pragma unroll
        for (int it = 0; it < 4; it++) {
            const int item = wave * 4 + it;
            const f32x4* hr = reinterpret_cast<const f32x4*>(&h2buf[item][0]);
            float o = 0.f;
#pragma unroll
            for (int k = 0; k < 16; k++) {
                f32x4 h = hr[k], w = wcr[k];
                o += h[0] * w[0] + h[1] * w[1] + h[2] * w[2] + h[3] * w[3];
            }
            out[(size_t)(b0 + item) * NUM_CLASSES + lane] = o;
        }
    }
}

extern "C" void kernel_launch(void* const* d_in, const int* in_sizes, int n_in,
                              void* d_out, int out_size, void* d_ws, size_t ws_size,
                              hipStream_t stream) {
    const float* feat = nullptr;      // 100000*512  = 51,200,000
    const float* w1 = nullptr;        // 64*1024     = 65,536
    const float* w2 = nullptr;        // 64*128      = 8,192
    const float* wcls = nullptr;      // 16*64       = 1,024
    const int* nodes = nullptr;       // 16,384
    const int* neigh_idx = nullptr;   // 100000*5    = 500,000
    for (int i = 0; i < n_in; i++) {
        switch (in_sizes[i]) {
            case 51200000: feat = (const float*)d_in[i]; break;
            case 65536:    w1 = (const float*)d_in[i]; break;
            case 8192:     w2 = (const float*)d_in[i]; break;
            case 1024:     wcls = (const float*)d_in[i]; break;
            case 16384:    nodes = (const int*)d_in[i]; break;
            case 500000:   neigh_idx = (const int*)d_in[i]; break;
            default: break;
        }
    }
    float* out = (float*)d_out;  // [16384,16] fp32

    // ws layout: [0..4) nodes-dtype flag; [256..) packed w1 bf16 (131072 B);
    // PQ bf16 [100000][128] (25.6 MB); H1 bf16 [100000][64] (12.8 MB).
    int* flag = (int*)d_ws;
    short* w1p = (short*)((char*)d_ws + 256);
    short* PQ  = (short*)((char*)d_ws + 256 + 131072);
    short* H1  = (short*)((char*)d_ws + 256 + 131072 + (size_t)N_NODES * 128 * 2);

    prep<<<256, 256, 0, stream>>>(w1, w1p, nodes, flag);
    pq_gemm<<<512, 512, 0, stream>>>(feat, w1p, PQ);
    h1_combine<<<(N_NODES * 8 + 255) / 256, 256, 0, stream>>>(PQ, neigh_idx, H1);
    layer2_cls<<<BATCH / 16, 256, 0, stream>>>(H1, nodes, neigh_idx, w2, wcls, flag, out);
}